// Round 8
// baseline (434.757 us; speedup 1.0000x reference)
//
#include <hip/hip_runtime.h>
#include <stdint.h>

#define NN 100000      // nodes
#define EE 500000      // edges
#define HIDD 256
#define LN_EPS 1e-5f

typedef _Float16 half8 __attribute__((ext_vector_type(8)));  // 8 fp16 (4 VGPRs)
typedef _Float16 half4 __attribute__((ext_vector_type(4)));
typedef __fp16 fp16x2 __attribute__((ext_vector_type(2)));   // builtin return type
typedef float f32x4 __attribute__((ext_vector_type(4)));
typedef float f32x2 __attribute__((ext_vector_type(2)));     // v_pk_*_f32 carrier

// lgkm-only barrier: LDS writes visible WITHOUT draining vmcnt (global loads fly on).
#define LBAR() asm volatile("s_waitcnt lgkmcnt(0)\n\ts_barrier" ::: "memory")

__device__ __forceinline__ unsigned short f2h(float f) {
  _Float16 h = (_Float16)f;
  union { _Float16 hh; unsigned short us; } u; u.hh = h;
  return u.us;
}

__device__ __forceinline__ unsigned pkrtz(float a, float b) {
  union { fp16x2 h; unsigned u; } c;
  c.h = __builtin_amdgcn_cvt_pkrtz(a, b);
  return c.u;
}

__device__ __forceinline__ float fast_silu(float y) {
  float e = __expf(-y);
  return y * __builtin_amdgcn_rcpf(1.f + e);
}

__device__ __forceinline__ half8 ldg8(const unsigned short* p) {
  return *(const half8*)p;                  // global_load_dwordx4
}

// 8 consecutive f32 -> packed fp16 int4
__device__ __forceinline__ int4 cvt_row(const float* s) {
  float4 a0 = *(const float4*)s, a1 = *(const float4*)(s + 4);
  uint4 ua;
  ua.x = pkrtz(a0.x, a0.y); ua.y = pkrtz(a0.z, a0.w);
  ua.z = pkrtz(a1.x, a1.y); ua.w = pkrtz(a1.z, a1.w);
  return *(int4*)&ua;
}

// =======================  P-precompute PATH  =======================
// z1[e] = P1[spawn[e]] + P2[exist[e]] + W1f^T feat[e]
//   P1 = h @ W1[0:256] + b1  (b1 folded here — free; removes per-edge bias add),
//   P2 = h @ W1[256:512].  P fp16 [node][512].

// ---- prep_w: weight swizzles (712 blocks x 256 = 182272) ----
__global__ __launch_bounds__(256) void prep_w(const float* __restrict__ W1,
                                              const float* __restrict__ W2,
                                              const float* __restrict__ W3,
                                              unsigned short* __restrict__ wc,
                                              unsigned short* __restrict__ w1f,
                                              unsigned short* __restrict__ w2sw,
                                              unsigned short* __restrict__ w3sw) {
  int t = blockIdx.x * 256 + threadIdx.x;
  if (t < 131072) {
    int kq = t >> 12, mm = (t >> 3) & 511, j = t & 7;
    int k = kq * 8 + j;                       // 0..255
    int row = k + ((mm < 256) ? 0 : 256);
    wc[t] = f2h(W1[row * 256 + (mm & 255)]);
  } else if (t < 147456) {
    int t2 = t - 131072;
    int kq = t2 >> 11, m = (t2 >> 3) & 255, j = t2 & 7;
    int k = 512 + kq * 8 + j;
    w1f[t2] = f2h((k < 551) ? W1[k * 256 + m] : 0.f);
  } else if (t < 180224) {
    int t2 = t - 147456;
    int chunk = t2 >> 13, rem = t2 & 8191;
    int kq = rem >> 10, n = (rem >> 3) & 127, j = rem & 7;
    int k = (chunk << 6) + (kq << 3) + j;
    w2sw[t2] = f2h(W2[k * 128 + n]);
  } else if (t < 182272) {
    int t3 = t - 180224;
    int kq = t3 >> 7, o = (t3 >> 3) & 15, j = t3 & 7;
    int k = (kq << 3) + j;
    w3sw[t3] = f2h((o < 5) ? W3[k * 5 + o] : 0.f);
  }
}

// ---- pgemm v2: P[100000][512] fp16 = h @ Wcat (+b1 on cols 0..255) ----
// 1563 blocks x 64 nodes; BOTH col-halves per block (h staged ONCE -> half the
// h HBM traffic and half the blocks of v1). 256 thr / 4 waves; wave owns 64 cols.
__global__ __launch_bounds__(256) void pgemm(const float* __restrict__ h,
                                             const float* __restrict__ b1,
                                             const unsigned short* __restrict__ wc,
                                             unsigned short* __restrict__ Pb) {
  __shared__ short hl[16384];   // [64 rows][256 el] swz, 32 KB
  const int nb = blockIdx.x * 64;
  const int t = threadIdx.x;
  const int lane = t & 63;
  const int wv = t >> 6;
  const int cl = lane & 15;
  const int q = lane >> 4;
  const int sx = (cl & 7) << 3;

  const int row0 = t >> 3, p0 = t & 7;
  const int row1 = row0 + 32;
  const int n0 = (nb + row0 < NN) ? nb + row0 : NN - 1;
  const int n1 = (nb + row1 < NN) ? nb + row1 : NN - 1;
  const int sw0e = (row0 & 7) << 3;
  const int sw1e = (row1 & 7) << 3;
#pragma unroll
  for (int c = 0; c < 4; ++c) {
    int4 v0 = cvt_row(h + (size_t)n0 * 256 + c * 64 + p0 * 8);
    int4 v1 = cvt_row(h + (size_t)n1 * 256 + c * 64 + p0 * 8);
    *(int4*)&hl[row0 * 256 + ((c * 64 + p0 * 8) ^ sw0e)] = v0;
    *(int4*)&hl[row1 * 256 + ((c * 64 + p0 * 8) ^ sw1e)] = v1;
  }
  LBAR();

#pragma unroll
  for (int ch = 0; ch < 2; ++ch) {
    const unsigned short* wcp = wc + q * 4096 + (size_t)(ch * 256 + wv * 64 + cl) * 8;
    f32x4 acc[4][4];
    if (ch == 0) {
#pragma unroll
      for (int i = 0; i < 4; ++i) {
        float4 bv = *(const float4*)(b1 + wv * 64 + i * 16 + q * 4);
#pragma unroll
        for (int j = 0; j < 4; ++j) acc[i][j] = (f32x4){bv.x, bv.y, bv.z, bv.w};
      }
    } else {
#pragma unroll
      for (int i = 0; i < 4; ++i)
#pragma unroll
        for (int j = 0; j < 4; ++j) acc[i][j] = (f32x4){0.f, 0.f, 0.f, 0.f};
    }
#pragma unroll
    for (int c = 0; c < 4; ++c)
#pragma unroll
      for (int ks = 0; ks < 2; ++ks) {
        half8 bf[4], fX[4];
#pragma unroll
        for (int j = 0; j < 4; ++j)
          bf[j] = *(const half8*)&hl[(j * 16 + cl) * 256 + ((c * 64 + ks * 32 + q * 8) ^ sx)];
#pragma unroll
        for (int i = 0; i < 4; ++i) fX[i] = ldg8(wcp + (c * 2 + ks) * 16384 + i * 128);
#pragma unroll
        for (int i = 0; i < 4; ++i)
#pragma unroll
          for (int j = 0; j < 4; ++j)
            acc[i][j] = __builtin_amdgcn_mfma_f32_16x16x32_f16(fX[i], bf[j], acc[i][j], 0, 0, 0);
      }
#pragma unroll
    for (int i = 0; i < 4; ++i)
#pragma unroll
      for (int j = 0; j < 4; ++j) {
        int n = nb + cl + 16 * j;
        if (n < NN) {
          int mm = ch * 256 + wv * 64 + i * 16 + q * 4;
          uint2 w;
          w.x = pkrtz(acc[i][j][0], acc[i][j][1]);
          w.y = pkrtz(acc[i][j][2], acc[i][j][3]);
          *(uint2*)(Pb + (size_t)n * 512 + mm) = w;
        }
      }
  }
}

// ---- edge kernel (P path): 64 edges/block, 256 threads, 4 blocks/CU ----
// r7 lesson: main kernel latency-bound at 31% occ, arch VGPR 68, no staging dbuf
// -> r1's spill hazard is gone. feats now ALIASES r1 head (r1 idle during GEMM1;
// red1's barrier separates feats reads from z1T writes) -> LDS ~36.5KB -> 4/CU.
// P loads in 2 batches (16+16 half4 per batch) to cap in-flight regs (~100 peak).
// b1 is inside P1 (pgemm) — LN1 epilogue has no bias add.
struct __align__(16) SMemN {
  short r1[16384];    // feats [64][64]swz (head, GEMM1) -> z1T [64][256]swz -> z2T [64][128]swz
  float red[512];     // LN partials -> out staging (320f)
  _Float16 g1h[256], be1h[256];
  _Float16 b2h[128], g2h[128], be2h[128];
  float muv[16];
  float b3v[8];
  int spI[64], exI[64];
};  // ~36.5 KB -> 4 blocks/CU (146 KB < 160 KB)

__global__ __launch_bounds__(256, 4)
void edge_head_main(const float* __restrict__ x,
                    const int* __restrict__ spawn, const int* __restrict__ exist,
                    const float* __restrict__ insx, const int* __restrict__ insa,
                    const int* __restrict__ insc,
                    const float* __restrict__ g1, const float* __restrict__ be1,
                    const float* __restrict__ b2, const float* __restrict__ g2,
                    const float* __restrict__ be2,
                    const float* __restrict__ b3, const float* __restrict__ mu,
                    const float* __restrict__ gammaP,
                    const unsigned short* __restrict__ w1f,
                    const unsigned short* __restrict__ w2sw,
                    const unsigned short* __restrict__ w3swg,
                    const unsigned short* __restrict__ Pb,
                    float* __restrict__ out) {
  __shared__ SMemN sm;
  const int t = threadIdx.x;
  const int base = blockIdx.x * 64;
  const int lane = t & 63;
  const int wv = t >> 6;
  const int cl = lane & 15;
  const int q = lane >> 4;
  const int sx = (cl & 7) << 3;

  // ---- const staging ----
  sm.g1h[t] = (_Float16)g1[t]; sm.be1h[t] = (_Float16)be1[t];
  if (t < 128) { sm.b2h[t] = (_Float16)b2[t]; sm.g2h[t] = (_Float16)g2[t]; sm.be2h[t] = (_Float16)be2[t]; }
  if (t < 16) sm.muv[t] = mu[t];
  if (t < 8) sm.b3v[t] = (t < 5) ? b3[t] : 0.f;
  if (t < 64) {
    int e = base + t; int ec = e < EE ? e : EE - 1;
    sm.spI[t] = spawn[ec]; sm.exI[t] = exist[ec];
  }
  const float gma = gammaP[0];

  LBAR();   // B0: indices + consts visible

  // ---- P gather bases (lane's edge for n-tile j is cl+16j) ----
  const unsigned short* pb1[4];
  const unsigned short* pb2[4];
#pragma unroll
  for (int j = 0; j < 4; ++j) {
    int n = cl + 16 * j;
    pb1[j] = Pb + (size_t)sm.spI[n] * 512 + wv * 64 + q * 4;
    pb2[j] = Pb + (size_t)sm.exI[n] * 512 + 256 + wv * 64 + q * 4;
  }
  // batch A: i = 0,1 (32 half4 loads issued now)
  half4 p1a[2][4], p2a[2][4];
#pragma unroll
  for (int i2 = 0; i2 < 2; ++i2)
#pragma unroll
    for (int j = 0; j < 4; ++j) p1a[i2][j] = *(const half4*)(pb1[j] + i2 * 16);
#pragma unroll
  for (int i2 = 0; i2 < 2; ++i2)
#pragma unroll
    for (int j = 0; j < 4; ++j) p2a[i2][j] = *(const half4*)(pb2[j] + i2 * 16);

  // ---- wave 0: build features chunk -> r1 head (K rows 512..575) ----
  if (t < 64) {
    int e = base + t; int ec = e < EE ? e : EE - 1;
    float ix0 = insx[ec * 3], ix1 = insx[ec * 3 + 1], ix2 = insx[ec * 3 + 2];
    int nd = sm.exI[t];
    float dx = ix0 - x[nd * 3], dy = ix1 - x[nd * 3 + 1], dz = ix2 - x[nd * 3 + 2];
    float d = fmaxf(sqrtf(dx * dx + dy * dy + dz * dz), 1e-6f);
    int k1 = 16 + insa[ec], k2 = 32 + insc[ec];
    short* rp = &sm.r1[t * 64];
    const int sw = t & 7;
    float rb[16];
#pragma unroll
    for (int k = 0; k < 16; ++k) { float dd = d - sm.muv[k]; rb[k] = __expf(-gma * dd * dd); }
    uint4 ua, ub;
    ua.x = pkrtz(rb[0], rb[1]);  ua.y = pkrtz(rb[2], rb[3]);
    ua.z = pkrtz(rb[4], rb[5]);  ua.w = pkrtz(rb[6], rb[7]);
    ub.x = pkrtz(rb[8], rb[9]);  ub.y = pkrtz(rb[10], rb[11]);
    ub.z = pkrtz(rb[12], rb[13]); ub.w = pkrtz(rb[14], rb[15]);
    *(int4*)&rp[(0 ^ sw) * 8] = *(int4*)&ua;
    *(int4*)&rp[(1 ^ sw) * 8] = *(int4*)&ub;
    const int4 z4 = {0, 0, 0, 0};
#pragma unroll
    for (int g = 2; g < 8; ++g) *(int4*)&rp[(g ^ sw) * 8] = z4;
    rp[((k1 >> 3) ^ sw) * 8 + (k1 & 7)] = (short)0x3C00;   // fp16 1.0
    rp[((k2 >> 3) ^ sw) * 8 + (k2 & 7)] = (short)0x3C00;
  }

  // batch B: i = 2,3
  half4 p1b[2][4], p2b[2][4];
#pragma unroll
  for (int i2 = 0; i2 < 2; ++i2)
#pragma unroll
    for (int j = 0; j < 4; ++j) p1b[i2][j] = *(const half4*)(pb1[j] + (2 + i2) * 16);
#pragma unroll
  for (int i2 = 0; i2 < 2; ++i2)
#pragma unroll
    for (int j = 0; j < 4; ++j) p2b[i2][j] = *(const half4*)(pb2[j] + (2 + i2) * 16);

  LBAR();   // feats visible (P loads still in flight — lgkm-only barrier)

  // ---- acc = P1 + P2, then 32 feat MFMAs ----
  f32x4 acc[4][4];
#pragma unroll
  for (int i2 = 0; i2 < 2; ++i2)
#pragma unroll
    for (int j = 0; j < 4; ++j) {
      f32x4 a;
      a[0] = (float)p1a[i2][j][0] + (float)p2a[i2][j][0];
      a[1] = (float)p1a[i2][j][1] + (float)p2a[i2][j][1];
      a[2] = (float)p1a[i2][j][2] + (float)p2a[i2][j][2];
      a[3] = (float)p1a[i2][j][3] + (float)p2a[i2][j][3];
      acc[i2][j] = a;
    }
#pragma unroll
  for (int i2 = 0; i2 < 2; ++i2)
#pragma unroll
    for (int j = 0; j < 4; ++j) {
      f32x4 a;
      a[0] = (float)p1b[i2][j][0] + (float)p2b[i2][j][0];
      a[1] = (float)p1b[i2][j][1] + (float)p2b[i2][j][1];
      a[2] = (float)p1b[i2][j][2] + (float)p2b[i2][j][2];
      a[3] = (float)p1b[i2][j][3] + (float)p2b[i2][j][3];
      acc[2 + i2][j] = a;
    }
  {
    const unsigned short* w1fp = w1f + q * 2048 + wv * 512 + cl * 8;
#pragma unroll
    for (int ks = 0; ks < 2; ++ks) {
      half8 bf[4], fX[4];
#pragma unroll
      for (int j = 0; j < 4; ++j)
        bf[j] = *(const half8*)&sm.r1[(j * 16 + cl) * 64 + ((ks * 32 + q * 8) ^ sx)];
#pragma unroll
      for (int i = 0; i < 4; ++i) fX[i] = ldg8(w1fp + ks * 8192 + i * 128);
#pragma unroll
      for (int i = 0; i < 4; ++i)
#pragma unroll
        for (int j = 0; j < 4; ++j)
          acc[i][j] = __builtin_amdgcn_mfma_f32_16x16x32_f16(fX[i], bf[j], acc[i][j], 0, 0, 0);
    }
  }

  // ---- LN over 256 channels (bias already in P1), SiLU, pack z1T ----
  float S1arr[4], Q1arr[4];
#pragma unroll
  for (int j = 0; j < 4; ++j) {
    f32x2 S2 = (f32x2){0.f, 0.f}, Q2 = (f32x2){0.f, 0.f};
#pragma unroll
    for (int i = 0; i < 4; ++i) {
      f32x2 v0 = (f32x2){acc[i][j][0], acc[i][j][1]};
      f32x2 v1 = (f32x2){acc[i][j][2], acc[i][j][3]};
      S2 += v0 + v1;
      Q2 += v0 * v0;
      Q2 += v1 * v1;
    }
    float S = S2[0] + S2[1], Q = Q2[0] + Q2[1];
    S += __shfl_xor(S, 16); S += __shfl_xor(S, 32);
    Q += __shfl_xor(Q, 16); Q += __shfl_xor(Q, 32);
    S1arr[j] = S; Q1arr[j] = Q;
  }
  if (q == 0) {
#pragma unroll
    for (int j = 0; j < 4; ++j) {
      sm.red[wv * 64 + j * 16 + cl] = S1arr[j];
      sm.red[256 + wv * 64 + j * 16 + cl] = Q1arr[j];
    }
  }
  LBAR();   // red1 visible; ALL waves past feats reads -> r1 reusable as z1T
  f32x2 rs1[4], mr1[4];
#pragma unroll
  for (int j = 0; j < 4; ++j) {
    int m = j * 16 + cl;
    float S = sm.red[m] + sm.red[64 + m] + sm.red[128 + m] + sm.red[192 + m];
    float Q = sm.red[256 + m] + sm.red[320 + m] + sm.red[384 + m] + sm.red[448 + m];
    float mn = S * (1.f / 256.f);
    float rs = rsqrtf(Q * (1.f / 256.f) - mn * mn + LN_EPS);
    rs1[j] = (f32x2){rs, rs};
    mr1[j] = (f32x2){-mn * rs, -mn * rs};
  }
#pragma unroll
  for (int i = 0; i < 4; ++i) {
    half4 g4 = *(const half4*)&sm.g1h[wv * 64 + i * 16 + q * 4];
    half4 e4 = *(const half4*)&sm.be1h[wv * 64 + i * 16 + q * 4];
    f32x2 gg0 = (f32x2){(float)g4[0], (float)g4[1]}, gg1 = (f32x2){(float)g4[2], (float)g4[3]};
    f32x2 ee0 = (f32x2){(float)e4[0], (float)e4[1]}, ee1 = (f32x2){(float)e4[2], (float)e4[3]};
#pragma unroll
    for (int j = 0; j < 4; ++j) {
      f32x2 v0 = (f32x2){acc[i][j][0], acc[i][j][1]};
      f32x2 v1 = (f32x2){acc[i][j][2], acc[i][j][3]};
      f32x2 t0 = v0 * rs1[j] + mr1[j];
      f32x2 t1 = v1 * rs1[j] + mr1[j];
      f32x2 y0 = t0 * gg0 + ee0;
      f32x2 y1 = t1 * gg1 + ee1;
      float s0 = fast_silu(y0[0]), s1 = fast_silu(y0[1]);
      float s2 = fast_silu(y1[0]), s3 = fast_silu(y1[1]);
      uint2 w; w.x = pkrtz(s0, s1); w.y = pkrtz(s2, s3);
      int m = j * 16 + cl;
      int k0 = wv * 64 + i * 16 + q * 4;
      *(uint2*)&sm.r1[m * 256 + (k0 ^ ((m & 7) << 3))] = w;   // z1T swz
    }
  }
  LBAR();   // z1T visible

  half8 af3[4];
#pragma unroll
  for (int ks = 0; ks < 4; ++ks)
    af3[ks] = ldg8(w3swg + (ks * 4 + q) * 128 + cl * 8);

  // ---- GEMM2 ----
  const unsigned short* w2p = w2sw + q * 1024 + wv * 256 + cl * 8;
  f32x4 acc2[2][4];
#pragma unroll
  for (int i = 0; i < 2; ++i)
#pragma unroll
    for (int j = 0; j < 4; ++j) acc2[i][j] = (f32x4){0.f, 0.f, 0.f, 0.f};
#pragma unroll
  for (int c2 = 0; c2 < 4; ++c2) {
#pragma unroll
    for (int ks = 0; ks < 2; ++ks) {
      half8 a0 = ldg8(w2p + c2 * 8192 + ks * 4096);
      half8 a1 = ldg8(w2p + c2 * 8192 + ks * 4096 + 128);
      half8 bf[4];
#pragma unroll
      for (int j = 0; j < 4; ++j)
        bf[j] = *(const half8*)&sm.r1[(j * 16 + cl) * 256 + ((c2 * 64 + ks * 32 + q * 8) ^ sx)];
#pragma unroll
      for (int j = 0; j < 4; ++j) {
        acc2[0][j] = __builtin_amdgcn_mfma_f32_16x16x32_f16(a0, bf[j], acc2[0][j], 0, 0, 0);
        acc2[1][j] = __builtin_amdgcn_mfma_f32_16x16x32_f16(a1, bf[j], acc2[1][j], 0, 0, 0);
      }
    }
  }

  // ---- +b2, LN over 128, SiLU, pack z2T ----
  f32x2 bb2[2][2];
#pragma unroll
  for (int i = 0; i < 2; ++i) {
    half4 b4 = *(const half4*)&sm.b2h[wv * 32 + i * 16 + q * 4];
    bb2[i][0] = (f32x2){(float)b4[0], (float)b4[1]};
    bb2[i][1] = (f32x2){(float)b4[2], (float)b4[3]};
  }
  float S2arr[4], Q2arr[4];
#pragma unroll
  for (int j = 0; j < 4; ++j) {
    f32x2 S2 = (f32x2){0.f, 0.f}, Q2 = (f32x2){0.f, 0.f};
#pragma unroll
    for (int i = 0; i < 2; ++i) {
      f32x2 v0 = (f32x2){acc2[i][j][0], acc2[i][j][1]} + bb2[i][0];
      f32x2 v1 = (f32x2){acc2[i][j][2], acc2[i][j][3]} + bb2[i][1];
      acc2[i][j][0] = v0[0]; acc2[i][j][1] = v0[1];
      acc2[i][j][2] = v1[0]; acc2[i][j][3] = v1[1];
      S2 += v0 + v1;
      Q2 += v0 * v0;
      Q2 += v1 * v1;
    }
    float S = S2[0] + S2[1], Q = Q2[0] + Q2[1];
    S += __shfl_xor(S, 16); S += __shfl_xor(S, 32);
    Q += __shfl_xor(Q, 16); Q += __shfl_xor(Q, 32);
    S2arr[j] = S; Q2arr[j] = Q;
  }
  if (q == 0) {
#pragma unroll
    for (int j = 0; j < 4; ++j) {
      sm.red[wv * 64 + j * 16 + cl] = S2arr[j];
      sm.red[256 + wv * 64 + j * 16 + cl] = Q2arr[j];
    }
  }
  LBAR();   // red2 visible; z1T dead -> z2T region safe
  f32x2 rs2[4], mr2[4];
#pragma unroll
  for (int j = 0; j < 4; ++j) {
    int m = j * 16 + cl;
    float S = sm.red[m] + sm.red[64 + m] + sm.red[128 + m] + sm.red[192 + m];
    float Q = sm.red[256 + m] + sm.red[320 + m] + sm.red[384 + m] + sm.red[448 + m];
    float mn = S * (1.f / 128.f);
    float rs = rsqrtf(Q * (1.f / 128.f) - mn * mn + LN_EPS);
    rs2[j] = (f32x2){rs, rs};
    mr2[j] = (f32x2){-mn * rs, -mn * rs};
  }
#pragma unroll
  for (int i = 0; i < 2; ++i) {
    half4 g4 = *(const half4*)&sm.g2h[wv * 32 + i * 16 + q * 4];
    half4 e4 = *(const half4*)&sm.be2h[wv * 32 + i * 16 + q * 4];
    f32x2 gg0 = (f32x2){(float)g4[0], (float)g4[1]}, gg1 = (f32x2){(float)g4[2], (float)g4[3]};
    f32x2 ee0 = (f32x2){(float)e4[0], (float)e4[1]}, ee1 = (f32x2){(float)e4[2], (float)e4[3]};
#pragma unroll
    for (int j = 0; j < 4; ++j) {
      f32x2 v0 = (f32x2){acc2[i][j][0], acc2[i][j][1]};
      f32x2 v1 = (f32x2){acc2[i][j][2], acc2[i][j][3]};
      f32x2 t0 = v0 * rs2[j] + mr2[j];
      f32x2 t1 = v1 * rs2[j] + mr2[j];
      f32x2 y0 = t0 * gg0 + ee0;
      f32x2 y1 = t1 * gg1 + ee1;
      float s0 = fast_silu(y0[0]), s1 = fast_silu(y0[1]);
      float s2 = fast_silu(y1[0]), s3 = fast_silu(y1[1]);
      uint2 w; w.x = pkrtz(s0, s1); w.y = pkrtz(s2, s3);
      int m = j * 16 + cl;
      int k0 = wv * 32 + i * 16 + q * 4;
      *(uint2*)&sm.r1[m * 128 + (k0 ^ ((m & 7) << 3))] = w;   // z2T swz
    }
  }
  LBAR();   // z2T visible

  // ---- GEMM3 + staged coalesced output ----
  f32x4 a3 = (f32x4){0.f, 0.f, 0.f, 0.f};
  const int m3 = wv * 16 + cl;
  const int sx3 = (m3 & 7) << 3;
#pragma unroll
  for (int ks = 0; ks < 4; ++ks) {
    half8 bfv = *(const half8*)&sm.r1[m3 * 128 + ((ks * 32 + q * 8) ^ sx3)];
    a3 = __builtin_amdgcn_mfma_f32_16x16x32_f16(af3[ks], bfv, a3, 0, 0, 0);
  }
#pragma unroll
  for (int r = 0; r < 4; ++r) {
    int o = q * 4 + r;
    if (o < 5) sm.red[m3 * 5 + o] = a3[r] + sm.b3v[o];
  }
  LBAR();
  if (t < 80) {
    size_t g = (size_t)base * 5 + (size_t)t * 4;
    if (g + 4 <= (size_t)EE * 5) {
      *(float4*)(out + g) = *(const float4*)&sm.red[t * 4];
    } else {
#pragma unroll
      for (int u = 0; u < 4; ++u)
        if (g + u < (size_t)EE * 5) out[g + u] = sm.red[t * 4 + u];
    }
  }
}

// =======================  FALLBACK PATH (r5, f32-h gathers)  =======================
__global__ __launch_bounds__(256) void prep_fb(const float* __restrict__ W1,
                                               const float* __restrict__ W2,
                                               const float* __restrict__ W3,
                                               unsigned short* __restrict__ w1sw,
                                               unsigned short* __restrict__ w2sw,
                                               unsigned short* __restrict__ w3sw) {
  int t = blockIdx.x * 256 + threadIdx.x;
  if (t < 147456) {
    int chunk = t >> 14, rem = t & 16383;
    int kq = rem >> 11, n = (rem >> 3) & 255, j = rem & 7;
    int k = (chunk << 6) + (kq << 3) + j;
    w1sw[t] = f2h((k < 551) ? W1[k * 256 + n] : 0.f);
  } else if (t < 180224) {
    int t2 = t - 147456;
    int chunk = t2 >> 13, rem = t2 & 8191;
    int kq = rem >> 10, n = (rem >> 3) & 127, j = rem & 7;
    int k = (chunk << 6) + (kq << 3) + j;
    w2sw[t2] = f2h(W2[k * 128 + n]);
  } else if (t < 182272) {
    int t3 = t - 180224;
    int kq = t3 >> 7, o = (t3 >> 3) & 15, j = t3 & 7;
    int k = (kq << 3) + j;
    w3sw[t3] = f2h((o < 5) ? W3[k * 5 + o] : 0.f);
  }
}

struct __align__(16) SMemF {
  short r1[16384];
  short feats[4096];
  float red[512];
  _Float16 b1h[256], g1h[256], be1h[256];
  _Float16 b2h[128], g2h[128], be2h[128];
  float muv[16];
  float b3v[8];
  int spI[64], exI[64];
};

__global__ __launch_bounds__(256, 3)
void edge_head_fb(const float* __restrict__ h, const float* __restrict__ x,
                  const int* __restrict__ spawn, const int* __restrict__ exist,
                  const float* __restrict__ insx, const int* __restrict__ insa,
                  const int* __restrict__ insc,
                  const float* __restrict__ b1, const float* __restrict__ g1,
                  const float* __restrict__ be1,
                  const float* __restrict__ b2, const float* __restrict__ g2,
                  const float* __restrict__ be2,
                  const float* __restrict__ b3, const float* __restrict__ mu,
                  const float* __restrict__ gammaP,
                  const unsigned short* __restrict__ w1sw,
                  const unsigned short* __restrict__ w2sw,
                  const unsigned short* __restrict__ w3swg,
                  float* __restrict__ out) {
  __shared__ SMemF sm;
  const int t = threadIdx.x;
  const int base = blockIdx.x * 64;
  const int lane = t & 63;
  const int wv = t >> 6;
  const int cl = lane & 15;
  const int q = lane >> 4;
  const int sx = (cl & 7) << 3;

  sm.b1h[t] = (_Float16)b1[t]; sm.g1h[t] = (_Float16)g1[t]; sm.be1h[t] = (_Float16)be1[t];
  if (t < 128) { sm.b2h[t] = (_Float16)b2[t]; sm.g2h[t] = (_Float16)g2[t]; sm.be2h[t] = (_Float16)be2[t]; }
  if (t < 16) sm.muv[t] = mu[t];
  if (t < 8) sm.b3v[t] = (t < 5) ? b3[t] : 0.f;
  if (t < 64) {
    int e = base + t; int ec = e < EE ? e : EE - 1;
    sm.spI[t] = spawn[ec]; sm.exI[t] = exist[ec];
  }
  const float gma = gammaP[0];
  LBAR();

  float dreg = 0.f;
  int k1 = 16, k2 = 32;
  if (t < 64) {
    int e = base + t; int ec = e < EE ? e : EE - 1;
    float ix0 = insx[ec * 3], ix1 = insx[ec * 3 + 1], ix2 = insx[ec * 3 + 2];
    int nd = sm.exI[t];
    float dx = ix0 - x[nd * 3], dy = ix1 - x[nd * 3 + 1], dz = ix2 - x[nd * 3 + 2];
    dreg = fmaxf(sqrtf(dx * dx + dy * dy + dz * dz), 1e-6f);
    k1 = 16 + insa[ec]; k2 = 32 + insc[ec];
  }

  const int row0 = t >> 3, p0 = t & 7;
  const int row1 = row0 + 32;
  const int sw0 = ((p0 ^ (row0 & 7)) << 3);
  const int sw1 = ((p0 ^ (row1 & 7)) << 3);

  const float* bSp0 = h + (size_t)sm.spI[row0] * HIDD + p0 * 8;
  const float* bSp1 = h + (size_t)sm.spI[row1] * HIDD + p0 * 8;
  const float* bEx0 = h + (size_t)sm.exI[row0] * HIDD + p0 * 8;
  const float* bEx1 = h + (size_t)sm.exI[row1] * HIDD + p0 * 8;

  int4 pS0, pS1, pS2, pS3;
#define GLOAD2F(ph) do {                                                \
    const float* b0_ = ((ph) < 2) ? bSp0 : bEx0;                        \
    const float* b1_ = ((ph) < 2) ? bSp1 : bEx1;                        \
    const int ce_ = ((ph) & 1) * 128;                                   \
    pS0 = cvt_row(b0_ + ce_);                                           \
    pS1 = cvt_row(b1_ + ce_);                                           \
    pS2 = cvt_row(b0_ + ce_ + 64);                                      \
    pS3 = cvt_row(b1_ + ce_ + 64);                                      \
  } while (0)

  GLOAD2F(0);
  *(int4*)&sm.r1[row0 * 64 + sw0] = pS0;
  *(int4*)&sm.r1[row1 * 64 + sw1] = pS1;
  *(int4*)&sm.r1[4096 + row0 * 64 + sw0] = pS2;
  *(int4*)&sm.r1[4096 + row1 * 64 + sw1] = pS3;
  GLOAD2F(1);

  const unsigned short* w1p = w1sw + q * 2048 + wv * 512 + cl * 8;

  if (t < 64) {
    short* rp = &sm.feats[t * 64];
    const int sw = t & 7;
    float rb[16];
#pragma unroll
    for (int k = 0; k < 16; ++k) { float dd = dreg - sm.muv[k]; rb[k] = __expf(-gma * dd * dd); }
    uint4 ua, ub;
    ua.x = pkrtz(rb[0], rb[1]);  ua.y = pkrtz(rb[2], rb[3]);
    ua.z = pkrtz(rb[4], rb[5]);  ua.w = pkrtz(rb[6], rb[7]);
    ub.x = pkrtz(rb[8], rb[9]);  ub.y = pkrtz(rb[10], rb[11]);
    ub.z = pkrtz(rb[12], rb[13]); ub.w = pkrtz(rb[14], rb[15]);
    *(int4*)&rp[(0 ^ sw) * 8] = *(int4*)&ua;
    *(int4*)&rp[(1 ^ sw) * 8] = *(int4*)&ub;
    const int4 z4 = {0, 0, 0, 0};
#pragma unroll
    for (int g = 2; g < 8; ++g) *(int4*)&rp[(g ^ sw) * 8] = z4;
    rp[((k1 >> 3) ^ sw) * 8 + (k1 & 7)] = (short)0x3C00;
    rp[((k2 >> 3) ^ sw) * 8 + (k2 & 7)] = (short)0x3C00;
  }
  LBAR();

  f32x4 acc[4][4];
#pragma unroll
  for (int i = 0; i < 4; ++i)
#pragma unroll
    for (int j = 0; j < 4; ++j) acc[i][j] = (f32x4){0.f, 0.f, 0.f, 0.f};

#pragma unroll
  for (int p = 0; p < 4; ++p) {
    if (p < 3) {
      const int nb = ((p + 1) & 1) * 8192;
      *(int4*)&sm.r1[nb + row0 * 64 + sw0] = pS0;
      *(int4*)&sm.r1[nb + row1 * 64 + sw1] = pS1;
      *(int4*)&sm.r1[nb + 4096 + row0 * 64 + sw0] = pS2;
      *(int4*)&sm.r1[nb + 4096 + row1 * 64 + sw1] = pS3;
      if (p < 2) GLOAD2F(p + 2);
    }
    const int cb = (p & 1) * 8192;
#pragma unroll
    for (int ch = 0; ch < 2; ++ch) {
      const unsigned short* wp = w1p + (2 * p + ch) * 16384;
#pragma unroll
      for (int ks = 0; ks < 2; ++ks) {
        half8 bf[4], fX[4];
#pragma unroll
        for (int j = 0; j < 4; ++j)
          bf[j] = *(const half8*)&sm.r1[cb + ch * 4096 + (j * 16 + cl) * 64 + ((ks * 32 + q * 8) ^ sx)];
#pragma unroll
        for (int i = 0; i < 4; ++i) fX[i] = ldg8(wp + ks * 8192 + i * 128);
#pragma unroll
        for (int i = 0; i < 4; ++i)
#pragma unroll
          for (int j = 0; j < 4; ++j)
            acc[i][j] = __builtin_amdgcn_mfma_f32_16x16x32_f16(fX[i], bf[j], acc[i][j], 0, 0, 0);
      }
    }
    if (p < 3) LBAR();
  }
#undef GLOAD2F

  {
    const unsigned short* wp = w1p + 8 * 16384;
#pragma unroll
    for (int ks = 0; ks < 2; ++ks) {
      half8 bf[4], fX[4];
#pragma unroll
      for (int j = 0; j < 4; ++j)
        bf[j] = *(const half8*)&sm.feats[(j * 16 + cl) * 64 + ((ks * 32 + q * 8) ^ sx)];
#pragma unroll
      for (int i = 0; i < 4; ++i) fX[i] = ldg8(wp + ks * 8192 + i * 128);
#pragma unroll
      for (int i = 0; i < 4; ++i)
#pragma unroll
        for (int j = 0; j < 4; ++j)
          acc[i][j] = __builtin_amdgcn_mfma_f32_16x16x32_f16(fX[i], bf[j], acc[i][j], 0, 0, 0);
    }
  }

  f32x2 bb1[4][2];
#pragma unroll
  for (int i = 0; i < 4; ++i) {
    half4 b4 = *(const half4*)&sm.b1h[wv * 64 + i * 16 + q * 4];
    bb1[i][0] = (f32x2){(float)b4[0], (float)b4[1]};
    bb1[i][1] = (f32x2){(float)b4[2], (float)b4[3]};
  }
  float S1arr[4], Q1arr[4];
#pragma unroll
  for (int j = 0; j < 4; ++j) {
    f32x2 S2 = (f32x2){0.f, 0.f}, Q2 = (f32x2){0.f, 0.f};
#pragma unroll
    for (int i = 0; i < 4; ++i) {
      f32x2 v0 = (f32x2){acc[i][j][0], acc[i][j][1]} + bb1[i][0];
      f32x2 v1 = (f32x2){acc[i][j][2], acc[i][j][3]} + bb1[i][1];
      acc[i][j][0] = v0[0]; acc[i][j][1] = v0[1];
      acc[i][j][2] = v1[0]; acc[i][j][3] = v1[1];
      S2 += v0 + v1; Q2 += v0 * v0; Q2 += v1 * v1;
    }
    float S = S2[0] + S2[1], Q = Q2[0] + Q2[1];
    S += __shfl_xor(S, 16); S += __shfl_xor(S, 32);
    Q += __shfl_xor(Q, 16); Q += __shfl_xor(Q, 32);
    S1arr[j] = S; Q1arr[j] = Q;
  }
  if (q == 0) {
#pragma unroll
    for (int j = 0; j < 4; ++j) {
      sm.red[wv * 64 + j * 16 + cl] = S1arr[j];
      sm.red[256 + wv * 64 + j * 16 + cl] = Q1arr[j];
    }
  }
  LBAR();
  f32x2 rs1[4], mr1[4];
#pragma unroll
  for (int j = 0; j < 4; ++j) {
    int m = j * 16 + cl;
    float S = sm.red[m] + sm.red[64 + m] + sm.red[128 + m] + sm.red[192 + m];
    float Q = sm.red[256 + m] + sm.red[320 + m] + sm.red[384 + m] + sm.red[448 + m];
    float mn = S * (1.f / 256.f);
    float rs = rsqrtf(Q * (1.f / 256.f) - mn * mn + LN_EPS);
    rs1[j] = (f32x2){rs, rs};
    mr1[j] = (f32x2){-mn * rs, -mn * rs};
  }
#pragma unroll
  for (int i = 0; i < 4; ++i) {
    half4 g4 = *(const half4*)&sm.g1h[wv * 64 + i * 16 + q * 4];
    half4 e4 = *(const half4*)&sm.be1h[wv * 64 + i * 16 + q * 4];
    f32x2 gg0 = (f32x2){(float)g4[0], (float)g4[1]}, gg1 = (f32x2){(float)g4[2], (float)g4[3]};
    f32x2 ee0 = (f32x2){(float)e4[0], (float)e4[1]}, ee1 = (f32x2){(float)e4[2], (float)e4[3]};
#pragma unroll
    for (int j = 0; j < 4; ++j) {
      f32x2 v0 = (f32x2){acc[i][j][0], acc[i][j][1]};
      f32x2 v1 = (f32x2){acc[i][j][2], acc[i][j][3]};
      f32x2 t0 = v0 * rs1[j] + mr1[j];
      f32x2 t1 = v1 * rs1[j] + mr1[j];
      f32x2 y0 = t0 * gg0 + ee0;
      f32x2 y1 = t1 * gg1 + ee1;
      float s0 = fast_silu(y0[0]), s1 = fast_silu(y0[1]);
      float s2 = fast_silu(y1[0]), s3 = fast_silu(y1[1]);
      uint2 w; w.x = pkrtz(s0, s1); w.y = pkrtz(s2, s3);
      int m = j * 16 + cl;
      int k0 = wv * 64 + i * 16 + q * 4;
      *(uint2*)&sm.r1[m * 256 + (k0 ^ ((m & 7) << 3))] = w;
    }
  }
  LBAR();

  half8 af3[4];
#pragma unroll
  for (int ks = 0; ks < 4; ++ks)
    af3[ks] = ldg8(w3swg + (ks * 4 + q) * 128 + cl * 8);

  const unsigned short* w2p = w2sw + q * 1024 + wv * 256 + cl * 8;
  f32x4 acc2[2][4];
#pragma unroll
  for (int i = 0; i < 2; ++i)
#pragma unroll
    for (int j = 0; j < 4; ++j) acc2[i][j] = (f32x4){0.f, 0.f, 0.f, 0.f};
#pragma unroll
  for (int c2 = 0; c2 < 4; ++c2) {
#pragma unroll
    for (int ks = 0; ks < 2; ++ks) {
      half8 a0 = ldg8(w2p + c2 * 8192 + ks * 4096);
      half8 a1 = ldg8(w2p + c2 * 8192 + ks * 4096 + 128);
      half8 bf[4];
#pragma unroll
      for (int j = 0; j < 4; ++j)
        bf[j] = *(const half8*)&sm.r1[(j * 16 + cl) * 256 + ((c2 * 64 + ks * 32 + q * 8) ^ sx)];
#pragma unroll
      for (int j = 0; j < 4; ++j) {
        acc2[0][j] = __builtin_amdgcn_mfma_f32_16x16x32_f16(a0, bf[j], acc2[0][j], 0, 0, 0);
        acc2[1][j] = __builtin_amdgcn_mfma_f32_16x16x32_f16(a1, bf[j], acc2[1][j], 0, 0, 0);
      }
    }
  }

  f32x2 bb2[2][2];
#pragma unroll
  for (int i = 0; i < 2; ++i) {
    half4 b4 = *(const half4*)&sm.b2h[wv * 32 + i * 16 + q * 4];
    bb2[i][0] = (f32x2){(float)b4[0], (float)b4[1]};
    bb2[i][1] = (f32x2){(float)b4[2], (float)b4[3]};
  }
  float S2arr[4], Q2arr[4];
#pragma unroll
  for (int j = 0; j < 4; ++j) {
    f32x2 S2 = (f32x2){0.f, 0.f}, Q2 = (f32x2){0.f, 0.f};
#pragma unroll
    for (int i = 0; i < 2; ++i) {
      f32x2 v0 = (f32x2){acc2[i][j][0], acc2[i][j][1]} + bb2[i][0];
      f32x2 v1 = (f32x2){acc2[i][j][2], acc2[i][j][3]} + bb2[i][1];
      acc2[i][j][0] = v0[0]; acc2[i][j][1] = v0[1];
      acc2[i][j][2] = v1[0]; acc2[i][j][3] = v1[1];
      S2 += v0 + v1; Q2 += v0 * v0; Q2 += v1 * v1;
    }
    float S = S2[0] + S2[1], Q = Q2[0] + Q2[1];
    S += __shfl_xor(S, 16); S += __shfl_xor(S, 32);
    Q += __shfl_xor(Q, 16); Q += __shfl_xor(Q, 32);
    S2arr[j] = S; Q2arr[j] = Q;
  }
  if (q == 0) {
#pragma unroll
    for (int j = 0; j < 4; ++j) {
      sm.red[wv * 64 + j * 16 + cl] = S2arr[j];
      sm.red[256 + wv * 64 + j * 16 + cl] = Q2arr[j];
    }
  }
  LBAR();
  f32x2 rs2[4], mr2[4];
#pragma unroll
  for (int j = 0; j < 4; ++j) {
    int m = j * 16 + cl;
    float S = sm.red[m] + sm.red[64 + m] + sm.red[128 + m] + sm.red[192 + m];
    float Q = sm.red[256 + m] + sm.red[320 + m] + sm.red[384 + m] + sm.red[448 + m];
    float mn = S * (1.f / 128.f);
    float rs = rsqrtf(Q * (1.f / 128.f) - mn * mn + LN_EPS);
    rs2[j] = (f32x2){rs, rs};
    mr2[j] = (f32x2){-mn * rs, -mn * rs};
  }
#pragma unroll
  for (int i = 0; i < 2; ++i) {
    half4 g4 = *(const half4*)&sm.g2h[wv * 32 + i * 16 + q * 4];
    half4 e4 = *(const half4*)&sm.be2h[wv * 32 + i * 16 + q * 4];
    f32x2 gg0 = (f32x2){(float)g4[0], (float)g4[1]}, gg1 = (f32x2){(float)g4[2], (float)g4[3]};
    f32x2 ee0 = (f32x2){(float)e4[0], (float)e4[1]}, ee1 = (f32x2){(float)e4[2], (float)e4[3]};
#pragma unroll
    for (int j = 0; j < 4; ++j) {
      f32x2 v0 = (f32x2){acc2[i][j][0], acc2[i][j][1]};
      f32x2 v1 = (f32x2){acc2[i][j][2], acc2[i][j][3]};
      f32x2 t0 = v0 * rs2[j] + mr2[j];
      f32x2 t1 = v1 * rs2[j] + mr2[j];
      f32x2 y0 = t0 * gg0 + ee0;
      f32x2 y1 = t1 * gg1 + ee1;
      float s0 = fast_silu(y0[0]), s1 = fast_silu(y0[1]);
      float s2 = fast_silu(y1[0]), s3 = fast_silu(y1[1]);
      uint2 w; w.x = pkrtz(s0, s1); w.y = pkrtz(s2, s3);
      int m = j * 16 + cl;
      int k0 = wv * 32 + i * 16 + q * 4;
      *(uint2*)&sm.r1[m * 128 + (k0 ^ ((m & 7) << 3))] = w;
    }
  }
  LBAR();

  f32x4 a3 = (f32x4){0.f, 0.f, 0.f, 0.f};
  const int m3 = wv * 16 + cl;
  const int sx3 = (m3 & 7) << 3;
#pragma unroll
  for (int ks = 0; ks < 4; ++ks) {
    half8 bfv = *(const half8*)&sm.r1[m3 * 128 + ((ks * 32 + q * 8) ^ sx3)];
    a3 = __builtin_amdgcn_mfma_f32_16x16x32_f16(af3[ks], bfv, a3, 0, 0, 0);
  }
#pragma unroll
  for (int r = 0; r < 4; ++r) {
    int o = q * 4 + r;
    if (o < 5) sm.red[m3 * 5 + o] = a3[r] + sm.b3v[o];
  }
  LBAR();
  if (t < 80) {
    size_t g = (size_t)base * 5 + (size_t)t * 4;
    if (g + 4 <= (size_t)EE * 5) {
      *(float4*)(out + g) = *(const float4*)&sm.red[t * 4];
    } else {
#pragma unroll
      for (int u = 0; u < 4; ++u)
        if (g + u < (size_t)EE * 5) out[g + u] = sm.red[t * 4 + u];
    }
  }
}

extern "C" void kernel_launch(void* const* d_in, const int* in_sizes, int n_in,
                              void* d_out, int out_size, void* d_ws, size_t ws_size,
                              hipStream_t stream) {
  const float* h    = (const float*)d_in[0];
  const float* x    = (const float*)d_in[1];
  const int* spawn  = (const int*)d_in[2];
  const int* exist  = (const int*)d_in[3];
  const float* insx = (const float*)d_in[4];
  const int* insa   = (const int*)d_in[5];
  const int* insc   = (const int*)d_in[6];
  const float* W1   = (const float*)d_in[7];
  const float* b1   = (const float*)d_in[8];
  const float* g1   = (const float*)d_in[9];
  const float* be1  = (const float*)d_in[10];
  const float* W2   = (const float*)d_in[11];
  const float* b2   = (const float*)d_in[12];
  const float* g2   = (const float*)d_in[13];
  const float* be2  = (const float*)d_in[14];
  const float* W3   = (const float*)d_in[15];
  const float* b3   = (const float*)d_in[16];
  const float* mu   = (const float*)d_in[17];
  const float* gma  = (const float*)d_in[18];

  const size_t needP = 364544ull + (size_t)NN * 512 * 2;   // weights + fp16 P
  if (ws_size >= needP) {
    unsigned short* wc   = (unsigned short*)d_ws;   // 131072 el
    unsigned short* w1f  = wc + 131072;             // 16384 el
    unsigned short* w2sw = w1f + 16384;             // 32768 el
    unsigned short* w3sw = w2sw + 32768;            // 2048 el
    unsigned short* Pb   = w3sw + 2048;             // NN*512 el fp16
    prep_w<<<712, 256, 0, stream>>>(W1, W2, W3, wc, w1f, w2sw, w3sw);
    pgemm<<<1563, 256, 0, stream>>>(h, b1, wc, Pb);
    edge_head_main<<<7813, 256, 0, stream>>>(x, spawn, exist, insx, insa, insc,
                                             g1, be1, b2, g2, be2, b3, mu, gma,
                                             w1f, w2sw, w3sw, Pb, (float*)d_out);
  } else {
    unsigned short* w1sw = (unsigned short*)d_ws;   // 147456 el
    unsigned short* w2sw = w1sw + 147456;           // 32768 el
    unsigned short* w3sw = w2sw + 32768;            // 2048 el
    prep_fb<<<712, 256, 0, stream>>>(W1, W2, W3, w1sw, w2sw, w3sw);
    edge_head_fb<<<7813, 256, 0, stream>>>(h, x, spawn, exist, insx, insa, insc,
                                           b1, g1, be1, b2, g2, be2, b3, mu, gma,
                                           w1sw, w2sw, w3sw, (float*)d_out);
  }
}